// Round 11
// baseline (29.398 us; speedup 1.0000x reference)
//
#include <hip/hip_runtime.h>

typedef short bf16x8 __attribute__((ext_vector_type(8)));
typedef float f32x4  __attribute__((ext_vector_type(4)));
typedef unsigned int u32;

#define HH 128
#define WW 128

__device__ __forceinline__ u32 cvt_pk_bf16(float lo, float hi) {
    u32 r;
    asm volatile("v_cvt_pk_bf16_f32 %0, %1, %2" : "=v"(r) : "v"(lo), "v"(hi));
    return r;   // low16 = bf16(lo), high16 = bf16(hi)
}

// ---------------------------------------------------------------------------
// Kernel 1 (prep): per-batch combined weights + bias into d_ws.
// ws layout: [16][1152] bf16x8 fragment-ordered weights (18432 B / batch),
// then at byte 294912: [16][32] float biases.
// ---------------------------------------------------------------------------
__global__ __launch_bounds__(256) void geps_prep_kernel(
    const float* __restrict__ codes, const float* __restrict__ weight,
    const float* __restrict__ A, const float* __restrict__ Bm,
    const float* __restrict__ bias, const float* __restrict__ bctx,
    bf16x8* __restrict__ wsw, float* __restrict__ wsb)
{
    __shared__ float lds_ctx[576];   // [i][r][kl] = sum_c A[i,c,kl]*codes[c,r]
    const int tid = threadIdx.x, b = blockIdx.x;
    const float c00 = codes[b * 4 + 0];
    const float c01 = codes[b * 4 + 1];
    const float c10 = codes[b * 4 + 2];
    const float c11 = codes[b * 4 + 3];

    for (int j = tid; j < 576; j += 256) {   // R10 bug: was `if (tid < 576)`
        int i = j / 18, rem = j % 18, r = rem / 9, kl = rem % 9;
        float a0 = A[(i * 2 + 0) * 9 + kl];
        float a1 = A[(i * 2 + 1) * 9 + kl];
        lds_ctx[j] = (r == 0) ? (a0 * c00 + a1 * c10) : (a0 * c01 + a1 * c11);
    }
    __syncthreads();

    for (int j = tid; j < 1152; j += 256) {
        int kl = j >> 7, rem = j & 127, o = rem >> 2, kb = rem & 3;
        float m0 = Bm[(o * 2 + 0) * 9 + kl];
        float m1 = Bm[(o * 2 + 1) * 9 + kl];
        float wf[8];
        #pragma unroll
        for (int jj = 0; jj < 8; ++jj) {
            int i = kb * 8 + jj;
            wf[jj] = weight[(o * 32 + i) * 9 + kl]
                   + lds_ctx[i * 18 + kl] * m0
                   + lds_ctx[i * 18 + 9 + kl] * m1;
        }
        u32 pk[4];
        #pragma unroll
        for (int q = 0; q < 4; ++q) pk[q] = cvt_pk_bf16(wf[2 * q], wf[2 * q + 1]);
        *(uint4*)&wsw[b * 1152 + kl * 128 + (o >> 4) * 64 + kb * 16 + (o & 15)] =
            make_uint4(pk[0], pk[1], pk[2], pk[3]);
    }
    if (tid < 32)
        wsb[b * 32 + tid] = bias[tid] + c00 * bctx[tid] + c11 * bctx[32 + tid];
}

// ---------------------------------------------------------------------------
// Kernel 2 (conv): implicit-GEMM conv, 9 shifted 32x32 channel GEMMs on
// mfma_f32_16x16x32_bf16.  SMALL blocks for CU-level phase diversity:
// 256 thr (4 waves) own 2 output rows x 128 cols x 32 out-ch; LDS = 32 KB
// (4 staged rows) -> 3 independent blocks/CU at different pipeline phases.
// Wave = (row 0..1, nh 0..1): 1 row, 4 col-tiles, all 32 o (B-frag -> 2 MFMA).
// A-frags + bias read from d_ws (L2-resident), issued before the barrier.
// Grid: 1024 blocks (16 b x 64 row-pairs), XCD-bijective swizzle.
// ---------------------------------------------------------------------------
__global__ __launch_bounds__(256, 3) void geps_conv_kernel(
    const float* __restrict__ x, const bf16x8* __restrict__ wsw,
    const float* __restrict__ wsb, float* __restrict__ out)
{
    __shared__ bf16x8 lds_x[2048];   // [4 slots][8 colslots][4 ig][16 p]

    const int tid = threadIdx.x;
    const int l   = tid & 63;
    const int wvid = tid >> 6;        // 0..3
    const int row = wvid >> 1;        // 0..1
    const int nh  = wvid & 1;         // col-tile half: nt = nh*4 + 0..3

    // XCD-aware bijective swizzle: 1024 blocks = 8 XCDs x 128 contiguous.
    const int orig = blockIdx.x;
    const int vb   = (orig & 7) * 128 + (orig >> 3);
    const int b    = vb >> 6;         // batch 0..15
    const int grp  = vb & 63;         // row-pair 0..63
    const int h0   = grp * 2;         // rows h0, h0+1

    // ---- Stage x rows h0-1..h0+2 -> slots 0..3 (channel-last bf16) ----
    #pragma unroll
    for (int it = 0; it < 4; ++it) {
        int idx = it * 256 + tid;     // < 1024
        int cp  = idx & 63;
        int ig  = (idx >> 6) & 3;
        int rr  = idx >> 8;           // 0..3
        int c0  = cp * 2;
        int grow = (h0 - 1 + rr) & 127;
        const float* src = x + ((size_t)(b * 32 + ig * 8) * HH + grow) * WW + c0;
        float2 f[8];
        #pragma unroll
        for (int jj = 0; jj < 8; ++jj)
            f[jj] = *(const float2*)(src + (size_t)jj * HH * WW);
        u32 p0[4], p1[4];
        #pragma unroll
        for (int q = 0; q < 4; ++q) {
            p0[q] = cvt_pk_bf16(f[2 * q].x, f[2 * q + 1].x);
            p1[q] = cvt_pk_bf16(f[2 * q].y, f[2 * q + 1].y);
        }
        int didx = rr * 512 + (c0 >> 4) * 64 + ig * 16 + (c0 & 15);
        *(uint4*)&lds_x[didx]     = make_uint4(p0[0], p0[1], p0[2], p0[3]);
        *(uint4*)&lds_x[didx + 1] = make_uint4(p1[0], p1[1], p1[2], p1[3]);
    }

    // ---- A-frags + bias from ws (global, L2-hit; latency overlaps barrier) ----
    const int awb = (l >> 4) * 16 + (l & 15);
    bf16x8 af[9][2];
    #pragma unroll
    for (int kl = 0; kl < 9; ++kl)
        #pragma unroll
        for (int oh = 0; oh < 2; ++oh)
            af[kl][oh] = wsw[b * 1152 + kl * 128 + oh * 64 + awb];

    float blr[2][4];
    #pragma unroll
    for (int oh = 0; oh < 2; ++oh)
        #pragma unroll
        for (int r = 0; r < 4; ++r)
            blr[oh][r] = wsb[b * 32 + oh * 16 + (l >> 4) * 4 + r];

    // ---- B-address bases per tap-column shift dl in {-1,0,1} ----
    const int p = l & 15, igf = l >> 4;
    int bb[3];
    #pragma unroll
    for (int dl = -1; dl <= 1; ++dl) {
        int pq = p + dl;                       // -1..16
        bb[dl + 1] = (pq & 15) + ((pq >> 4) << 6) + igf * 16;  // 16B-elem units
    }

    __syncthreads();

    // ---- Main loop: each B-frag ds_read_b128 feeds 2 MFMAs ----
    f32x4 acc[2][4];
    #pragma unroll
    for (int oh = 0; oh < 2; ++oh)
        #pragma unroll
        for (int q = 0; q < 4; ++q) acc[oh][q] = (f32x4){0.f, 0.f, 0.f, 0.f};

    #pragma unroll
    for (int lc = 0; lc < 3; ++lc) {
        #pragma unroll
        for (int k = 0; k < 3; ++k) {
            const bf16x8 a0 = af[k * 3 + lc][0];
            const bf16x8 a1 = af[k * 3 + lc][1];
            #pragma unroll
            for (int q = 0; q < 4; ++q) {
                int t = (bb[lc] + (nh * 4 + q) * 64) & 511;  // col wrap
                bf16x8 bfv = lds_x[(row + k) * 512 + t];
                acc[0][q] = __builtin_amdgcn_mfma_f32_16x16x32_bf16(
                    a0, bfv, acc[0][q], 0, 0, 0);
                acc[1][q] = __builtin_amdgcn_mfma_f32_16x16x32_bf16(
                    a1, bfv, acc[1][q], 0, 0, 0);
            }
        }
    }

    // ---- Epilogue: bias + store (D: col=lane&15 -> w, row=(lane>>4)*4+reg -> o) ----
    const int h = h0 + row;
    const size_t obase = ((size_t)(b * 32 + (l >> 4) * 4) * HH + h) * WW + p;
    #pragma unroll
    for (int oh = 0; oh < 2; ++oh)
        #pragma unroll
        for (int q = 0; q < 4; ++q)
            #pragma unroll
            for (int r = 0; r < 4; ++r)
                out[obase + (size_t)(oh * 16 + r) * (HH * WW) + (nh * 4 + q) * 16] =
                    acc[oh][q][r] + blr[oh][r];
}

extern "C" void kernel_launch(void* const* d_in, const int* in_sizes, int n_in,
                              void* d_out, int out_size, void* d_ws, size_t ws_size,
                              hipStream_t stream) {
    const float* x      = (const float*)d_in[0];
    const float* codes  = (const float*)d_in[1];
    const float* weight = (const float*)d_in[2];
    const float* A      = (const float*)d_in[3];
    const float* Bm     = (const float*)d_in[4];
    const float* bias   = (const float*)d_in[5];
    const float* bctx   = (const float*)d_in[6];
    float* out = (float*)d_out;

    bf16x8* wsw = (bf16x8*)d_ws;                          // 16*1152*16 = 294912 B
    float*  wsb = (float*)((char*)d_ws + 16 * 1152 * 16); // 16*32*4 = 2048 B

    hipLaunchKernelGGL(geps_prep_kernel, dim3(16), dim3(256), 0, stream,
                       codes, weight, A, Bm, bias, bctx, wsw, wsb);
    hipLaunchKernelGGL(geps_conv_kernel, dim3(1024), dim3(256), 0, stream,
                       x, wsw, wsb, out);
}

// Round 12
// 23.719 us; speedup vs baseline: 1.2394x; 1.2394x over previous
//
#include <hip/hip_runtime.h>

typedef short bf16x8 __attribute__((ext_vector_type(8)));
typedef float f32x4  __attribute__((ext_vector_type(4)));
typedef unsigned int u32;

#define HH 128
#define WW 128

__device__ __forceinline__ u32 cvt_pk_bf16(float lo, float hi) {
    u32 r;
    asm volatile("v_cvt_pk_bf16_f32 %0, %1, %2" : "=v"(r) : "v"(lo), "v"(hi));
    return r;   // low16 = bf16(lo), high16 = bf16(hi)
}

// LDS-only barrier: does NOT drain outstanding global stores (unlike
// __syncthreads(), which emits s_waitcnt vmcnt(0) before s_barrier).
__device__ __forceinline__ void lds_barrier() {
    asm volatile("s_waitcnt lgkmcnt(0)" ::: "memory");
    __builtin_amdgcn_s_barrier();
    __builtin_amdgcn_sched_barrier(0);
}

// Implicit-GEMM conv via 9 shifted 32x32 channel GEMMs on mfma_f32_16x16x32_bf16.
// Block: 512 thr (8 waves) owns 8 contiguous output rows; FOUR 2-row chunks
// through a rolling 6-slot LDS row buffer (slot = staged-row mod 6):
//   chunk c: [issue loads rows 4+2c,5+2c] [compute+store rows 2c,2c+1]
//            [cvt+ds_write prefetched rows] [LDS-only barrier]
// Stores are nontemporal fire-and-forget; barriers never wait on them ->
// read burst of c+1 / compute of c / store drain of c-1 all overlap.
// Wave = (row 0..1, nq 0..3): 1 row, 2 col-tiles, all 32 out-ch
//   (each B-frag ds_read_b128 feeds 2 MFMAs).
// Grid: 256 blocks (16 b x 16 groups), XCD-bijective swizzle, 1 block/CU.
__global__ __launch_bounds__(512, 1) void geps_mfma_kernel(
    const float* __restrict__ x, const float* __restrict__ codes,
    const float* __restrict__ weight, const float* __restrict__ A,
    const float* __restrict__ Bm, const float* __restrict__ bias,
    const float* __restrict__ bctx, float* __restrict__ out)
{
    // [6 slots][8 colslots][4 ig][16 p] x 8ch bf16 = 49152 B
    __shared__ bf16x8 lds_x[3072];
    // [9 kl][2 oh][4 kb][16 o] x 8i bf16 = 18432 B (A-frag = 1 linear b128)
    __shared__ bf16x8 lds_w[1152];
    __shared__ float  lds_ctx[576];   // [i][r][kl] = sum_c A[i,c,kl]*codes[c,r]
    __shared__ float  lds_b[32];

    const int tid  = threadIdx.x;
    const int l    = tid & 63;
    const int wvid = tid >> 6;         // 0..7
    const int row  = wvid >> 2;        // 0..1 (row within 2-row chunk)
    const int nq   = wvid & 3;         // 0..3 (col-tiles nq*2, nq*2+1)

    // XCD-aware bijective swizzle: 256 blocks = 8 XCDs x 32 contiguous.
    const int orig = blockIdx.x;
    const int vb   = (orig & 7) * 32 + (orig >> 3);
    const int b    = vb >> 4;          // batch 0..15
    const int grp  = vb & 15;          // 8-row group 0..15
    const int h0   = grp * 8;          // rows h0..h0+7

    const float c00 = codes[b * 4 + 0];
    const float c01 = codes[b * 4 + 1];
    const float c10 = codes[b * 4 + 2];
    const float c11 = codes[b * 4 + 3];

    // ---- Phase 1: code contraction + per-sample bias ----
    for (int j = tid; j < 576; j += 512) {
        int i = j / 18, rem = j % 18, r = rem / 9, kl = rem % 9;
        float a0 = A[(i * 2 + 0) * 9 + kl];
        float a1 = A[(i * 2 + 1) * 9 + kl];
        lds_ctx[j] = (r == 0) ? (a0 * c00 + a1 * c10) : (a0 * c01 + a1 * c11);
    }
    if (tid < 32) lds_b[tid] = bias[tid] + c00 * bctx[tid] + c11 * bctx[32 + tid];
    lds_barrier();   // barrier A: ctx visible

    // ---- Phase 2a: stage x rows h0-1..h0+2 -> slots 0..3 (x burst first) ----
    #pragma unroll
    for (int it = 0; it < 2; ++it) {
        int idx = it * 512 + tid;      // < 1024
        int cp  = idx & 63;
        int ig  = (idx >> 6) & 3;
        int rr  = idx >> 8;            // 0..3
        int c0  = cp * 2;
        int grow = (h0 - 1 + rr) & 127;
        const float* src = x + ((size_t)(b * 32 + ig * 8) * HH + grow) * WW + c0;
        float2 f[8];
        #pragma unroll
        for (int jj = 0; jj < 8; ++jj)
            f[jj] = *(const float2*)(src + (size_t)jj * HH * WW);
        u32 p0[4], p1[4];
        #pragma unroll
        for (int q = 0; q < 4; ++q) {
            p0[q] = cvt_pk_bf16(f[2 * q].x, f[2 * q + 1].x);
            p1[q] = cvt_pk_bf16(f[2 * q].y, f[2 * q + 1].y);
        }
        int didx = rr * 512 + (c0 >> 4) * 64 + ig * 16 + (c0 & 15);
        *(uint4*)&lds_x[didx]     = make_uint4(p0[0], p0[1], p0[2], p0[3]);
        *(uint4*)&lds_x[didx + 1] = make_uint4(p1[0], p1[1], p1[2], p1[3]);
    }

    // ---- Phase 2b: synthesize combined weights -> bf16 LDS (coalesced) ----
    for (int j = tid; j < 1152; j += 512) {
        int kl = j >> 7, rem = j & 127, o = rem >> 2, kb = rem & 3;
        float m0 = Bm[(o * 2 + 0) * 9 + kl];
        float m1 = Bm[(o * 2 + 1) * 9 + kl];
        float wf[8];
        #pragma unroll
        for (int jj = 0; jj < 8; ++jj) {
            int i = kb * 8 + jj;
            wf[jj] = weight[(o * 32 + i) * 9 + kl]
                   + lds_ctx[i * 18 + kl] * m0
                   + lds_ctx[i * 18 + 9 + kl] * m1;
        }
        u32 pk[4];
        #pragma unroll
        for (int q = 0; q < 4; ++q) pk[q] = cvt_pk_bf16(wf[2 * q], wf[2 * q + 1]);
        *(uint4*)&lds_w[kl * 128 + (o >> 4) * 64 + kb * 16 + (o & 15)] =
            make_uint4(pk[0], pk[1], pk[2], pk[3]);
    }
    lds_barrier();   // barrier B: slots 0..3 + weights ready

    // ---- A fragments: all 9 taps x both oh halves (72 VGPRs) ----
    const int awb = (l >> 4) * 16 + (l & 15);
    bf16x8 af[9][2];
    #pragma unroll
    for (int kl = 0; kl < 9; ++kl)
        #pragma unroll
        for (int oh = 0; oh < 2; ++oh)
            af[kl][oh] = lds_w[kl * 128 + oh * 64 + awb];

    // ---- B-address bases per tap-column shift dl in {-1,0,1} ----
    const int p = l & 15, igf = l >> 4;
    int bb[3];
    #pragma unroll
    for (int dl = -1; dl <= 1; ++dl) {
        int pq = p + dl;                       // -1..16
        bb[dl + 1] = (pq & 15) + ((pq >> 4) << 6) + igf * 16;  // 16B-elem units
    }

    float blr[2][4];
    #pragma unroll
    for (int oh = 0; oh < 2; ++oh)
        #pragma unroll
        for (int r = 0; r < 4; ++r)
            blr[oh][r] = lds_b[oh * 16 + (l >> 4) * 4 + r];

    const size_t obase0 = (size_t)(b * 32 + (l >> 4) * 4) * (HH * WW) + p;

    // ---- 4 chunks of 2 rows through the rolling buffer ----
    #pragma unroll
    for (int c = 0; c < 4; ++c) {
        // Issue next 2 rows' loads (rows rr = 4+2c, 5+2c); 1 item/thread.
        float2 pf[8];
        int pcp = 0, pig = 0, prr = 0;
        if (c < 3) {
            int idx = tid;             // 512 items = 2 rows
            pcp = idx & 63;
            pig = (idx >> 6) & 3;
            prr = 4 + 2 * c + (idx >> 8);
            int grow = (h0 - 1 + prr) & 127;
            const float* src =
                x + ((size_t)(b * 32 + pig * 8) * HH + grow) * WW + pcp * 2;
            #pragma unroll
            for (int jj = 0; jj < 8; ++jj)
                pf[jj] = *(const float2*)(src + (size_t)jj * HH * WW);
        }

        // Compute output rows h0+2c+row from slots (2c+row+k) mod 6.
        f32x4 acc[2][2];
        #pragma unroll
        for (int oh = 0; oh < 2; ++oh)
            #pragma unroll
            for (int q = 0; q < 2; ++q) acc[oh][q] = (f32x4){0.f, 0.f, 0.f, 0.f};

        const int hr = 2 * c + row;
        #pragma unroll
        for (int lc = 0; lc < 3; ++lc) {
            #pragma unroll
            for (int k = 0; k < 3; ++k) {
                int s = hr + k; s = (s >= 6) ? s - 6 : s;
                const bf16x8 a0 = af[k * 3 + lc][0];
                const bf16x8 a1 = af[k * 3 + lc][1];
                #pragma unroll
                for (int q = 0; q < 2; ++q) {
                    int t = (bb[lc] + (nq * 2 + q) * 64) & 511;  // col wrap
                    bf16x8 bfv = lds_x[s * 512 + t];
                    acc[0][q] = __builtin_amdgcn_mfma_f32_16x16x32_bf16(
                        a0, bfv, acc[0][q], 0, 0, 0);
                    acc[1][q] = __builtin_amdgcn_mfma_f32_16x16x32_bf16(
                        a1, bfv, acc[1][q], 0, 0, 0);
                }
            }
        }

        // Nontemporal stores (fire-and-forget; barriers won't wait on them).
        const size_t ob = obase0 + (size_t)(h0 + hr) * WW;
        #pragma unroll
        for (int oh = 0; oh < 2; ++oh)
            #pragma unroll
            for (int q = 0; q < 2; ++q)
                #pragma unroll
                for (int r = 0; r < 4; ++r)
                    __builtin_nontemporal_store(
                        acc[oh][q][r] + blr[oh][r],
                        &out[ob + (size_t)(oh * 16 + r) * (HH * WW) +
                             (nq * 2 + q) * 16]);

        // Convert + write prefetched rows to their slots (freed by chunk c-1).
        if (c < 3) {
            u32 p0[4], p1[4];
            #pragma unroll
            for (int q = 0; q < 4; ++q) {
                p0[q] = cvt_pk_bf16(pf[2 * q].x, pf[2 * q + 1].x);
                p1[q] = cvt_pk_bf16(pf[2 * q].y, pf[2 * q + 1].y);
            }
            int wslot = (prr >= 6) ? prr - 6 : prr;
            int c0 = pcp * 2;
            int didx = wslot * 512 + (c0 >> 4) * 64 + pig * 16 + (c0 & 15);
            *(uint4*)&lds_x[didx]     = make_uint4(p0[0], p0[1], p0[2], p0[3]);
            *(uint4*)&lds_x[didx + 1] = make_uint4(p1[0], p1[1], p1[2], p1[3]);
            lds_barrier();   // slots for chunk c+1 ready (LDS-only wait)
        }
    }
}

extern "C" void kernel_launch(void* const* d_in, const int* in_sizes, int n_in,
                              void* d_out, int out_size, void* d_ws, size_t ws_size,
                              hipStream_t stream) {
    const float* x      = (const float*)d_in[0];
    const float* codes  = (const float*)d_in[1];
    const float* weight = (const float*)d_in[2];
    const float* A      = (const float*)d_in[3];
    const float* Bm     = (const float*)d_in[4];
    const float* bias   = (const float*)d_in[5];
    const float* bctx   = (const float*)d_in[6];
    float* out = (float*)d_out;

    hipLaunchKernelGGL(geps_mfma_kernel, dim3(256), dim3(512), 0, stream,
                       x, codes, weight, A, Bm, bias, bctx, out);
}